// Round 5
// baseline (191.014 us; speedup 1.0000x reference)
//
#include <hip/hip_runtime.h>
#include <math.h>

#define M_DIM 8192
#define K_DIM 2048
#define N_DIM 4096
#define TOPK  82

typedef short short8 __attribute__((ext_vector_type(8)));
typedef float f32x4 __attribute__((ext_vector_type(4)));
typedef int   i32x4 __attribute__((ext_vector_type(4)));
typedef unsigned short ushort_t;
typedef unsigned long long u64;

#define VMWAIT(N) do { asm volatile("s_waitcnt vmcnt(" #N ")" ::: "memory"); \
                       __builtin_amdgcn_sched_barrier(0); } while(0)
#define LGKM0     do { asm volatile("s_waitcnt lgkmcnt(0)" ::: "memory"); \
                       __builtin_amdgcn_sched_barrier(0); } while(0)
__device__ __forceinline__ void barrier_fence(){
  __builtin_amdgcn_s_barrier();
  __builtin_amdgcn_sched_barrier(0);
}

__device__ __forceinline__ unsigned short f2bf(float f){
  unsigned u = __float_as_uint(f);
  unsigned r = (u + 0x7FFFu + ((u >> 16) & 1u)) >> 16;  // RNE; exact for 0.0/1.0
  return (unsigned short)r;
}

// async global->LDS, 16B per lane. LDS dest = wave-uniform base + lane*16.
__device__ __forceinline__ void gload16(const void* g, void* l){
  __builtin_amdgcn_global_load_lds(
      (const __attribute__((address_space(1))) unsigned int*)g,
      (__attribute__((address_space(3))) unsigned int*)l,
      16, 0, 0);
}

// ---------------- boost factor (fp64, once) ----------------
__global__ __launch_bounds__(256) void boost_kernel(const float* __restrict__ avg,
                                                    double* __restrict__ boost){
  __shared__ double sp[4];
  __shared__ double stot;
  int tid = threadIdx.x;
  int lane = tid & 63, w = tid >> 6;
  double s = 0.0;
  for (int i = 0; i < 16; ++i) s += (double)avg[tid + 256*i];
  for (int off = 32; off > 0; off >>= 1) s += __shfl_down(s, off, 64);
  if (lane == 0) sp[w] = s;
  __syncthreads();
  if (tid == 0) stot = sp[0] + sp[1] + sp[2] + sp[3];
  __syncthreads();
  double tot = stot;
  for (int i = 0; i < 16; ++i){
    int j = tid + 256*i;
    double a = (double)avg[j];
    double nb = (tot - a) / 4095.0;               // (total - avg)/(D-1)
    boost[j] = exp(-100.0 * (a - nb));
  }
}

// ---------------- A: fp32 -> i8 (binary), layout preserved [M][K] ----------
__global__ __launch_bounds__(256) void convA8_kernel(const float* __restrict__ X,
                                                     unsigned char* __restrict__ A8){
  size_t base = ((size_t)blockIdx.x * 256 + threadIdx.x) * 16;
  unsigned r[4];
  for (int q = 0; q < 4; ++q){
    float4 f = *(const float4*)&X[base + q*4];
    r[q] = (unsigned)(f.x != 0.f) | ((unsigned)(f.y != 0.f) << 8)
         | ((unsigned)(f.z != 0.f) << 16) | ((unsigned)(f.w != 0.f) << 24);
  }
  uint4 o; o.x = r[0]; o.y = r[1]; o.z = r[2]; o.w = r[3];
  *(uint4*)&A8[base] = o;
}

// ---------------- B: fp32 [K][N] -> i8 transposed [N][K] --------------------
__global__ __launch_bounds__(256) void convB8_kernel(const float* __restrict__ Cn,
                                                     unsigned char* __restrict__ B8){
  __shared__ float s[32][33];
  int tid = threadIdx.x;
  int bk = blockIdx.x & 63;        // K/32 = 64 tiles
  int bn = blockIdx.x >> 6;        // N/32 = 128 tiles
  int lr = tid >> 5, lc = tid & 31;
  for (int i = 0; i < 4; ++i)
    s[lr + 8*i][lc] = Cn[((size_t)(bk*32 + lr + 8*i))*N_DIM + bn*32 + lc];
  __syncthreads();
  for (int i = 0; i < 4; ++i)
    B8[((size_t)(bn*32 + lr + 8*i))*K_DIM + bk*32 + lc] =
        (unsigned char)(s[lc][lr + 8*i] != 0.f);
}

// ---------------- i8 GEMM, 256x256, 8-phase counted-vmcnt (T3+T4+T5) --------
// BK=128 split into 2 K-halves of 64B; LDS ring = [2 tiles][2 halves] per
// operand (4 x 16KB A + 4 x 16KB B = 128KB). Per phase (t,h):
//   vmcnt(counted, never 0 in steady state) -> barrier  (half (t,h) landed)
//   12x ds_read_b128 fragments -> lgkmcnt(0)+sched_barrier -> barrier
//   issue 4 gloads for half (t+2,h) into the just-freed slot
//   setprio(1); 32 MFMA; setprio(0)
// Chunk swizzle phys = chunk ^ (row&3), applied as inverse-swizzled global
// source (gload_lds dest stays linear) + swizzled ds_read (rule #21).
__global__ __launch_bounds__(512, 2) void gemm3_kernel(const unsigned char* __restrict__ A8,
                                                       const unsigned char* __restrict__ B8,
                                                       unsigned short* __restrict__ out){
  __shared__ unsigned char smem[131072];
  int tid = threadIdx.x;
  int lane = tid & 63, w = tid >> 6;
  unsigned bid = blockIdx.x;
  unsigned sw = (bid & 7u)*64u + (bid >> 3);   // XCD swizzle, 512%8==0 bijective
  int bn = sw & 15, bm = sw >> 4;
  int brow = bm*256, bcol = bn*256;
  int wr = w >> 2, wc = w & 3;                 // wave -> 128x64 output subtile
  int fr = lane & 15, fq = lane >> 4;
  int srow_off = lane >> 2;                    // staging: row within 16-row group
  int schunk = (lane & 3) ^ (srow_off & 3);    // inverse-swizzled source chunk

  i32x4 acc[8][4];
  #pragma unroll
  for (int m = 0; m < 8; ++m)
    #pragma unroll
    for (int n = 0; n < 4; ++n) acc[m][n] = (i32x4){0,0,0,0};

  auto stage = [&](int tb, int h, int kt){
    unsigned char* Ad = smem + (tb*2 + h)*16384;
    unsigned char* Bd = smem + 65536 + (tb*2 + h)*16384;
    int kbase = kt*128 + h*64;
    #pragma unroll
    for (int i = 0; i < 2; ++i){
      int R0 = w*32 + i*16;
      int r  = R0 + srow_off;
      gload16(A8 + ((size_t)(brow + r))*K_DIM + kbase + schunk*16, Ad + R0*64);
      gload16(B8 + ((size_t)(bcol + r))*K_DIM + kbase + schunk*16, Bd + R0*64);
    }
  };

  i32x4 a[8], b[4];
  auto load_frags = [&](int tb, int h){
    const unsigned char* Ah = smem + (tb*2 + h)*16384;
    const unsigned char* Bh = smem + 65536 + (tb*2 + h)*16384;
    int xc = (fq ^ (fr & 3)) * 16;             // swizzled chunk byte offset
    #pragma unroll
    for (int n = 0; n < 4; ++n){
      int r = wc*64 + n*16 + fr;
      b[n] = *(const i32x4*)&Bh[r*64 + xc];
    }
    #pragma unroll
    for (int m = 0; m < 8; ++m){
      int r = wr*128 + m*16 + fr;
      a[m] = *(const i32x4*)&Ah[r*64 + xc];
    }
  };

  auto mfma32 = [&](){
    __builtin_amdgcn_s_setprio(1);
    #pragma unroll
    for (int m = 0; m < 8; ++m)
      #pragma unroll
      for (int n = 0; n < 4; ++n)
        acc[m][n] = __builtin_amdgcn_mfma_i32_16x16x64_i8(a[m], b[n], acc[m][n], 0, 0, 0);
    __builtin_amdgcn_s_setprio(0);
  };

  stage(0, 0, 0); stage(0, 1, 0); stage(1, 0, 1); stage(1, 1, 1);   // 16 loads
  for (int t = 0; t < 16; ++t){
    int tb = t & 1;
    // ---- phase h=0: needs half (t,0); younger = (t,1),(t+1,0),(t+1,1) | (15,1)
    if (t < 15) VMWAIT(12); else VMWAIT(4);
    barrier_fence();
    load_frags(tb, 0);
    LGKM0;
    barrier_fence();                 // all waves' frags in regs -> slot free
    if (t < 14) stage(tb, 0, t + 2);
    mfma32();
    // ---- phase h=1: younger = (t+1,0),(t+1,1),(t+2,0) | (15,0),(15,1) | none
    if (t < 14) VMWAIT(12); else if (t == 14) VMWAIT(8); else VMWAIT(0);
    barrier_fence();
    load_frags(tb, 1);
    LGKM0;
    barrier_fence();
    if (t < 14) stage(tb, 1, t + 2);
    mfma32();
  }
  __syncthreads();

  // u16 epilogue: counts tile -> LDS, then coalesced 16B streams to global
  unsigned short* Ct = (unsigned short*)smem;
  #pragma unroll
  for (int m = 0; m < 8; ++m)
    #pragma unroll
    for (int n = 0; n < 4; ++n){
      int lr = wr*128 + m*16 + fq*4;
      int lc = wc*64 + n*16 + fr;
      #pragma unroll
      for (int j = 0; j < 4; ++j)
        Ct[(lr + j)*256 + lc] = (unsigned short)acc[m][n][j];
    }
  __syncthreads();
  #pragma unroll
  for (int q = 0; q < 16; ++q){
    int idx = q*8192 + tid*16;   // byte offset into the 128 KB tile
    int lr = idx >> 9;           // 512 B per local row
    int lcb = idx & 511;
    char* gp = (char*)(out + ((size_t)(brow + lr))*N_DIM + bcol) + lcb;
    *(uint4*)gp = *(const uint4*)&smem[idx];
  }
}

// ---------------- 2-phase 256^2 gemm (mid-ws float path, round-4 verified) --
template<typename OUT_T>
__global__ __launch_bounds__(512, 2) void gemm2_kernel(const unsigned char* __restrict__ A8,
                                                       const unsigned char* __restrict__ B8,
                                                       OUT_T* __restrict__ out){
  __shared__ unsigned char smem[131072];
  int tid = threadIdx.x;
  int lane = tid & 63, w = tid >> 6;
  unsigned bid = blockIdx.x;
  unsigned sw = (bid & 7u)*64u + (bid >> 3);
  int bn = sw & 15, bm = sw >> 4;
  int brow = bm*256, bcol = bn*256;
  int wr = w >> 2, wc = w & 3;
  int fr = lane & 15, fq = lane >> 4;
  int l8 = lane >> 3, slot = lane & 7;

  i32x4 acc[8][4];
  #pragma unroll
  for (int m = 0; m < 8; ++m)
    #pragma unroll
    for (int n = 0; n < 4; ++n) acc[m][n] = (i32x4){0,0,0,0};

  auto stage = [&](int c, int kt){
    unsigned char* As = smem + c*32768;
    unsigned char* Bs = smem + 65536 + c*32768;
    int kk = kt*128;
    #pragma unroll
    for (int q = 0; q < 4; ++q){
      int row = q*64 + w*8 + l8;
      int kb = slot ^ (row & 7);
      gload16(A8 + ((size_t)(brow+row))*K_DIM + kk + kb*16, As + q*8192 + w*1024);
      gload16(B8 + ((size_t)(bcol+row))*K_DIM + kk + kb*16, Bs + q*8192 + w*1024);
    }
  };

  stage(0, 0);
  __syncthreads();
  int cur = 0;
  for (int kt = 0; kt < 16; ++kt){
    if (kt < 15) stage(cur ^ 1, kt + 1);
    const unsigned char* As = smem + cur*32768;
    const unsigned char* Bs = smem + 65536 + cur*32768;
    #pragma unroll
    for (int ks = 0; ks < 2; ++ks){
      i32x4 b[4];
      #pragma unroll
      for (int n = 0; n < 4; ++n){
        int row = wc*64 + n*16 + fr;
        int sl = (ks*4 + fq) ^ (row & 7);
        b[n] = *(const i32x4*)&Bs[row*128 + sl*16];
      }
      #pragma unroll
      for (int mh = 0; mh < 2; ++mh){
        i32x4 a[4];
        #pragma unroll
        for (int mi = 0; mi < 4; ++mi){
          int row = wr*128 + (mh*4 + mi)*16 + fr;
          int sl = (ks*4 + fq) ^ (row & 7);
          a[mi] = *(const i32x4*)&As[row*128 + sl*16];
        }
        #pragma unroll
        for (int mi = 0; mi < 4; ++mi)
          #pragma unroll
          for (int n = 0; n < 4; ++n)
            acc[mh*4+mi][n] = __builtin_amdgcn_mfma_i32_16x16x64_i8(
                a[mi], b[n], acc[mh*4+mi][n], 0, 0, 0);
      }
    }
    __syncthreads();
    cur ^= 1;
  }
  #pragma unroll
  for (int m = 0; m < 8; ++m)
    #pragma unroll
    for (int n = 0; n < 4; ++n){
      int row = brow + wr*128 + m*16 + fq*4;
      int col = bcol + wc*64 + n*16 + fr;
      #pragma unroll
      for (int j = 0; j < 4; ++j)
        out[((size_t)(row + j))*N_DIM + col] = (OUT_T)acc[m][n][j];
    }
}

// ---------------- fallback GEMM (tiny ws): bf16 reg-staged ------------------
__global__ __launch_bounds__(256) void gemm_fb_kernel(const float* __restrict__ X,
                                                      const float* __restrict__ Cn,
                                                      float* __restrict__ out){
  __shared__ ushort_t As[128*32];
  __shared__ ushort_t Bs[128*32];
  int tid = threadIdx.x;
  int bn = blockIdx.x & 31, bm = blockIdx.x >> 5;
  int brow = bm * 128, bcol = bn * 128;
  int lane = tid & 63, w = tid >> 6;
  int wr = w >> 1, wc = w & 1;
  int fr = lane & 15, fq = lane >> 4;
  f32x4 acc[4][4];
  for (int m = 0; m < 4; ++m)
    for (int n = 0; n < 4; ++n)
      acc[m][n] = (f32x4){0.f, 0.f, 0.f, 0.f};
  int r2 = tid >> 1, h = tid & 1;
  int kr = tid >> 3, seg = tid & 7;
  for (int kk = 0; kk < K_DIM; kk += 32){
    __syncthreads();
    const float* ga = X + ((size_t)(brow + r2))*K_DIM + kk + h*16;
    unsigned pk[8];
    for (int q = 0; q < 4; ++q){
      float4 f = *(const float4*)(ga + q*4);
      pk[q*2]   = (unsigned)f2bf(f.x) | ((unsigned)f2bf(f.y) << 16);
      pk[q*2+1] = (unsigned)f2bf(f.z) | ((unsigned)f2bf(f.w) << 16);
    }
    uint4 u0; u0.x = pk[0]; u0.y = pk[1]; u0.z = pk[2]; u0.w = pk[3];
    uint4 u1; u1.x = pk[4]; u1.y = pk[5]; u1.z = pk[6]; u1.w = pk[7];
    *(uint4*)&As[r2*32 + h*16]     = u0;
    *(uint4*)&As[r2*32 + h*16 + 8] = u1;
    const float* gb = Cn + ((size_t)(kk + kr))*N_DIM + bcol + seg*16;
    for (int q = 0; q < 4; ++q){
      float4 f = *(const float4*)(gb + q*4);
      Bs[(seg*16 + q*4 + 0)*32 + kr] = f2bf(f.x);
      Bs[(seg*16 + q*4 + 1)*32 + kr] = f2bf(f.y);
      Bs[(seg*16 + q*4 + 2)*32 + kr] = f2bf(f.z);
      Bs[(seg*16 + q*4 + 3)*32 + kr] = f2bf(f.w);
    }
    __syncthreads();
    short8 a[4], b[4];
    for (int m = 0; m < 4; ++m) a[m] = *(const short8*)&As[(wr*64 + m*16 + fr)*32 + fq*8];
    for (int n = 0; n < 4; ++n) b[n] = *(const short8*)&Bs[(wc*64 + n*16 + fr)*32 + fq*8];
    for (int m = 0; m < 4; ++m)
      for (int n = 0; n < 4; ++n)
        acc[m][n] = __builtin_amdgcn_mfma_f32_16x16x32_bf16(a[m], b[n], acc[m][n], 0, 0, 0);
  }
  for (int m = 0; m < 4; ++m)
    for (int n = 0; n < 4; ++n){
      int row = brow + wr*64 + m*16 + fq*4;
      int col = bcol + wc*64 + n*16 + fr;
      for (int j = 0; j < 4; ++j)
        out[((size_t)(row + j))*N_DIM + col] = acc[m][n][j];
    }
}

// ---------------- per-row exact top-82 -> one-hot ---------------------------
// Two-level radix select on the DOUBLE bit pattern (positive doubles: value
// order == u64 bit order). Tie-break: lower index wins.
__device__ __forceinline__ void find_bin(unsigned* hist, unsigned* wtot,
                                         int* pB, int* pK, int tid, int Kt){
  int lane = tid & 63, w = tid >> 6;
  unsigned s = 0;
  #pragma unroll
  for (int b = 0; b < 16; ++b) s += hist[tid*16 + b];
  unsigned S = s;
  #pragma unroll
  for (int off = 1; off < 64; off <<= 1){
    unsigned T = __shfl_down(S, off, 64);
    if (lane + off < 64) S += T;
  }
  if (lane == 0) wtot[w] = S;          // whole-wave total (suffix at lane 0)
  __syncthreads();
  unsigned above = 0;
  for (int w2 = w + 1; w2 < 4; ++w2) above += wtot[w2];
  unsigned St = S + above;             // count with bin >= tid*16
  unsigned Sn = St - s;                // count with bin >= (tid+1)*16
  if (St >= (unsigned)Kt && Sn < (unsigned)Kt){   // exactly one thread
    unsigned cum = Sn;
    for (int b = 15; b >= 0; --b){
      unsigned hb = hist[tid*16 + b];
      cum += hb;
      if (cum >= (unsigned)Kt){ *pB = tid*16 + b; *pK = Kt - (int)(cum - hb); break; }
    }
  }
  __syncthreads();
}

template<typename CT>
__global__ __launch_bounds__(256) void topk_kernel(const CT* __restrict__ cnt,
                                                   float* __restrict__ outp,
                                                   const double* __restrict__ boost){
  __shared__ unsigned hist[4096];
  __shared__ unsigned wtot[4];
  __shared__ int sB, sK, sB2, sK2, scnt, sTi;
  __shared__ u64 sTv;
  __shared__ u64 cbits[256];
  __shared__ int cidx[256];
  int tid = threadIdx.x;
  const CT* rp = cnt + (size_t)blockIdx.x * N_DIM;
  float* wp = outp + (size_t)blockIdx.x * N_DIM;

  double v[16];
  unsigned bin[16];
  #pragma unroll
  for (int g = 0; g < 4; ++g){
    int c0 = g*1024 + tid*4;
    double4 bf = *(const double4*)&boost[c0];
    if constexpr (sizeof(CT) == 2){
      ushort4 f = *(const ushort4*)&rp[c0];
      v[g*4+0] = (double)f.x * bf.x;
      v[g*4+1] = (double)f.y * bf.y;
      v[g*4+2] = (double)f.z * bf.z;
      v[g*4+3] = (double)f.w * bf.w;
    } else {
      float4 f = *(const float4*)&rp[c0];
      v[g*4+0] = (double)f.x * bf.x;
      v[g*4+1] = (double)f.y * bf.y;
      v[g*4+2] = (double)f.z * bf.z;
      v[g*4+3] = (double)f.w * bf.w;
    }
  }
  #pragma unroll
  for (int e = 0; e < 16; ++e)
    bin[e] = (unsigned)(((u64)__double_as_longlong(v[e])) >> 51) & 4095u;

  #pragma unroll
  for (int i = 0; i < 16; ++i) hist[tid + 256*i] = 0u;
  __syncthreads();
  #pragma unroll
  for (int e = 0; e < 16; ++e) atomicAdd(&hist[bin[e]], 1u);
  __syncthreads();

  find_bin(hist, wtot, &sB, &sK, tid, TOPK);       // L1: boundary bin B, rank k1
  int B = sB, k1 = sK;

  #pragma unroll
  for (int i = 0; i < 16; ++i) hist[tid + 256*i] = 0u;
  if (tid == 0) scnt = 0;
  __syncthreads();
  #pragma unroll
  for (int e = 0; e < 16; ++e){
    if (bin[e] == (unsigned)B){
      unsigned b2 = (unsigned)(((u64)__double_as_longlong(v[e])) >> 39) & 4095u;
      atomicAdd(&hist[b2], 1u);
    }
  }
  __syncthreads();

  find_bin(hist, wtot, &sB2, &sK2, tid, k1);       // L2: sub-bin B2, rank k2
  int B2 = sB2, k2 = sK2;

  #pragma unroll
  for (int e = 0; e < 16; ++e){
    if (bin[e] == (unsigned)B){
      u64 ub = (u64)__double_as_longlong(v[e]);
      if ((unsigned)((ub >> 39) & 4095u) == (unsigned)B2){
        int pos = atomicAdd(&scnt, 1);
        if (pos < 256){
          int g = e >> 2, j = e & 3;
          cbits[pos] = ub;
          cidx[pos] = g*1024 + tid*4 + j;
        }
      }
    }
  }
  __syncthreads();
  int Csz = scnt; if (Csz > 256) Csz = 256;
  for (int i = tid; i < Csz; i += 256){
    u64 bi = cbits[i]; int xi = cidx[i];
    int rk = 0;
    for (int j2 = 0; j2 < Csz; ++j2){
      u64 bj = cbits[j2];
      rk += (int)((bj > bi) || (bj == bi && cidx[j2] < xi));
    }
    if (rk == k2 - 1){ sTv = bi; sTi = xi; }       // the exact K-th element
  }
  __syncthreads();
  double Tv = __longlong_as_double((long long)sTv);
  int Ti = sTi;
  #pragma unroll
  for (int g = 0; g < 4; ++g){
    int c0 = g*1024 + tid*4;
    float4 o;
    o.x = (v[g*4+0] > Tv || (v[g*4+0] == Tv && (c0+0) <= Ti)) ? 1.0f : 0.0f;
    o.y = (v[g*4+1] > Tv || (v[g*4+1] == Tv && (c0+1) <= Ti)) ? 1.0f : 0.0f;
    o.z = (v[g*4+2] > Tv || (v[g*4+2] == Tv && (c0+2) <= Ti)) ? 1.0f : 0.0f;
    o.w = (v[g*4+3] > Tv || (v[g*4+3] == Tv && (c0+3) <= Ti)) ? 1.0f : 0.0f;
    *(float4*)&wp[c0] = o;
  }
}

extern "C" void kernel_launch(void* const* d_in, const int* in_sizes, int n_in,
                              void* d_out, int out_size, void* d_ws, size_t ws_size,
                              hipStream_t stream){
  (void)in_sizes; (void)n_in; (void)out_size;
  const float* X   = (const float*)d_in[0];   // x [8192][2048]
  const float* Cn  = (const float*)d_in[1];   // connection [2048][4096]
  const float* avg = (const float*)d_in[2];   // avg_activation [4096]
  float* out = (float*)d_out;                 // [8192][4096]
  char* ws = (char*)d_ws;

  double* boost = (double*)ws;                                          // 32 KB
  const size_t offA = 65536;
  unsigned char* A8 = (unsigned char*)(ws + offA);                      // 16 MB
  unsigned char* B8 = (unsigned char*)(ws + offA + (size_t)16777216);   //  8 MB
  unsigned short* CNT = (unsigned short*)(ws + offA + (size_t)25165824);// 64 MB
  const size_t need_mid  = offA + (size_t)25165824;
  const size_t need_full = need_mid + (size_t)67108864;

  boost_kernel<<<dim3(1), dim3(256), 0, stream>>>(avg, boost);
  if (ws_size >= need_full){
    convA8_kernel<<<dim3(4096), dim3(256), 0, stream>>>(X, A8);
    convB8_kernel<<<dim3(8192), dim3(256), 0, stream>>>(Cn, B8);
    gemm3_kernel<<<dim3(512), dim3(512), 0, stream>>>(A8, B8, CNT);
    topk_kernel<unsigned short><<<dim3(8192), dim3(256), 0, stream>>>(CNT, out, boost);
  } else if (ws_size >= need_mid){
    convA8_kernel<<<dim3(4096), dim3(256), 0, stream>>>(X, A8);
    convB8_kernel<<<dim3(8192), dim3(256), 0, stream>>>(Cn, B8);
    gemm2_kernel<float><<<dim3(512), dim3(512), 0, stream>>>(A8, B8, out);
    topk_kernel<float><<<dim3(8192), dim3(256), 0, stream>>>(out, out, boost);
  } else {
    gemm_fb_kernel<<<dim3(2048), dim3(256), 0, stream>>>(X, Cn, out);
    topk_kernel<float><<<dim3(8192), dim3(256), 0, stream>>>(out, out, boost);
  }
}

// Round 6
// 180.521 us; speedup vs baseline: 1.0581x; 1.0581x over previous
//
#include <hip/hip_runtime.h>
#include <math.h>

#define M_DIM 8192
#define K_DIM 2048
#define N_DIM 4096
#define TOPK  82

typedef short short8 __attribute__((ext_vector_type(8)));
typedef float f32x4 __attribute__((ext_vector_type(4)));
typedef int   i32x4 __attribute__((ext_vector_type(4)));
typedef unsigned short ushort_t;
typedef unsigned long long u64;

#define VMWAIT(N) do { asm volatile("s_waitcnt vmcnt(" #N ")" ::: "memory"); \
                       __builtin_amdgcn_sched_barrier(0); } while(0)
#define LGKM0     do { asm volatile("s_waitcnt lgkmcnt(0)" ::: "memory"); \
                       __builtin_amdgcn_sched_barrier(0); } while(0)
__device__ __forceinline__ void barrier_fence(){
  __builtin_amdgcn_s_barrier();
  __builtin_amdgcn_sched_barrier(0);
}

__device__ __forceinline__ unsigned short f2bf(float f){
  unsigned u = __float_as_uint(f);
  unsigned r = (u + 0x7FFFu + ((u >> 16) & 1u)) >> 16;  // RNE; exact for 0.0/1.0
  return (unsigned short)r;
}

// async global->LDS, 16B per lane. LDS dest = wave-uniform base + lane*16.
__device__ __forceinline__ void gload16(const void* g, void* l){
  __builtin_amdgcn_global_load_lds(
      (const __attribute__((address_space(1))) unsigned int*)g,
      (__attribute__((address_space(3))) unsigned int*)l,
      16, 0, 0);
}

// ---------------- boost factor (fp64, once) ----------------
__global__ __launch_bounds__(256) void boost_kernel(const float* __restrict__ avg,
                                                    double* __restrict__ boost){
  __shared__ double sp[4];
  __shared__ double stot;
  int tid = threadIdx.x;
  int lane = tid & 63, w = tid >> 6;
  double s = 0.0;
  for (int i = 0; i < 16; ++i) s += (double)avg[tid + 256*i];
  for (int off = 32; off > 0; off >>= 1) s += __shfl_down(s, off, 64);
  if (lane == 0) sp[w] = s;
  __syncthreads();
  if (tid == 0) stot = sp[0] + sp[1] + sp[2] + sp[3];
  __syncthreads();
  double tot = stot;
  for (int i = 0; i < 16; ++i){
    int j = tid + 256*i;
    double a = (double)avg[j];
    double nb = (tot - a) / 4095.0;               // (total - avg)/(D-1)
    boost[j] = exp(-100.0 * (a - nb));
  }
}

// ---------------- A: fp32 -> i8 (binary), layout preserved [M][K] ----------
__global__ __launch_bounds__(256) void convA8_kernel(const float* __restrict__ X,
                                                     unsigned char* __restrict__ A8){
  size_t base = ((size_t)blockIdx.x * 256 + threadIdx.x) * 16;
  unsigned r[4];
  for (int q = 0; q < 4; ++q){
    float4 f = *(const float4*)&X[base + q*4];
    r[q] = (unsigned)(f.x != 0.f) | ((unsigned)(f.y != 0.f) << 8)
         | ((unsigned)(f.z != 0.f) << 16) | ((unsigned)(f.w != 0.f) << 24);
  }
  uint4 o; o.x = r[0]; o.y = r[1]; o.z = r[2]; o.w = r[3];
  *(uint4*)&A8[base] = o;
}

// ---------------- B: fp32 [K][N] -> i8 transposed [N][K] --------------------
__global__ __launch_bounds__(256) void convB8_kernel(const float* __restrict__ Cn,
                                                     unsigned char* __restrict__ B8){
  __shared__ float s[32][33];
  int tid = threadIdx.x;
  int bk = blockIdx.x & 63;        // K/32 = 64 tiles
  int bn = blockIdx.x >> 6;        // N/32 = 128 tiles
  int lr = tid >> 5, lc = tid & 31;
  for (int i = 0; i < 4; ++i)
    s[lr + 8*i][lc] = Cn[((size_t)(bk*32 + lr + 8*i))*N_DIM + bn*32 + lc];
  __syncthreads();
  for (int i = 0; i < 4; ++i)
    B8[((size_t)(bn*32 + lr + 8*i))*K_DIM + bk*32 + lc] =
        (unsigned char)(s[lc][lr + 8*i] != 0.f);
}

// ---------------- i8 GEMM, 256x256, 8-phase counted-vmcnt (T3+T4+T5) --------
// Schedule identical to round 5. LDS geometry fixed: PAIRED-ROW layout.
// Half-tile = 256 logical rows x 64B stored as 128 physical pairs of 128B.
// Logical (r, chunk c in 0..3) -> pair=r>>1, slot s=((r&1)*4+c)^(pair&7),
// byte = pair*128 + s*16. Fragment read (16 rows, fixed fq): s hits each of
// 8 values exactly twice -> 2 lanes/bank-quad = conflict-free (m136).
// global_load_lds dest stays linear (rule #21); per-lane global source is the
// inverse map: lane l -> slot s=l&7 of pair pl=l>>3, h=pl (group base has
// (R0/2)&7==0), so src row = R0 + 2*pl + ((s^h)>>2), chunk (s^h)&3.
__global__ __launch_bounds__(512, 2) void gemm3_kernel(const unsigned char* __restrict__ A8,
                                                       const unsigned char* __restrict__ B8,
                                                       unsigned short* __restrict__ out){
  __shared__ unsigned char smem[131072];
  int tid = threadIdx.x;
  int lane = tid & 63, w = tid >> 6;
  unsigned bid = blockIdx.x;
  unsigned sw = (bid & 7u)*64u + (bid >> 3);   // XCD swizzle, 512%8==0 bijective
  int bn = sw & 15, bm = sw >> 4;
  int brow = bm*256, bcol = bn*256;
  int wr = w >> 2, wc = w & 3;                 // wave -> 128x64 output subtile
  int fr = lane & 15, fq = lane >> 4;
  // staging decode (i-independent): lane writes slot s=lane&7 of pair pl
  int pl = lane >> 3;                          // pair within 16-row group
  int sx = (lane & 7) ^ (pl & 7);              // s ^ h
  int sp = sx >> 2;                            // source row parity
  int sc = sx & 3;                             // source chunk

  i32x4 acc[8][4];
  #pragma unroll
  for (int m = 0; m < 8; ++m)
    #pragma unroll
    for (int n = 0; n < 4; ++n) acc[m][n] = (i32x4){0,0,0,0};

  auto stage = [&](int tb, int h, int kt){
    unsigned char* Ad = smem + (tb*2 + h)*16384;
    unsigned char* Bd = smem + 65536 + (tb*2 + h)*16384;
    int kbase = kt*128 + h*64;
    #pragma unroll
    for (int i = 0; i < 2; ++i){
      int R0 = w*32 + i*16;
      int r  = R0 + 2*pl + sp;
      gload16(A8 + ((size_t)(brow + r))*K_DIM + kbase + sc*16, Ad + R0*64);
      gload16(B8 + ((size_t)(bcol + r))*K_DIM + kbase + sc*16, Bd + R0*64);
    }
  };

  i32x4 a[8], b[4];
  auto lds_off = [&](int r)->int{
    int pair = r >> 1;
    int s = (((r & 1) << 2) + fq) ^ (pair & 7);
    return pair*128 + s*16;
  };
  auto load_frags = [&](int tb, int h){
    const unsigned char* Ah = smem + (tb*2 + h)*16384;
    const unsigned char* Bh = smem + 65536 + (tb*2 + h)*16384;
    #pragma unroll
    for (int n = 0; n < 4; ++n)
      b[n] = *(const i32x4*)&Bh[lds_off(wc*64 + n*16 + fr)];
    #pragma unroll
    for (int m = 0; m < 8; ++m)
      a[m] = *(const i32x4*)&Ah[lds_off(wr*128 + m*16 + fr)];
  };

  auto mfma32 = [&](){
    __builtin_amdgcn_s_setprio(1);
    #pragma unroll
    for (int m = 0; m < 8; ++m)
      #pragma unroll
      for (int n = 0; n < 4; ++n)
        acc[m][n] = __builtin_amdgcn_mfma_i32_16x16x64_i8(a[m], b[n], acc[m][n], 0, 0, 0);
    __builtin_amdgcn_s_setprio(0);
  };

  stage(0, 0, 0); stage(0, 1, 0); stage(1, 0, 1); stage(1, 1, 1);   // 16 loads
  for (int t = 0; t < 16; ++t){
    int tb = t & 1;
    // ---- phase h=0: needs half (t,0); younger = (t,1),(t+1,0),(t+1,1) | (15,1)
    if (t < 15) VMWAIT(12); else VMWAIT(4);
    barrier_fence();
    load_frags(tb, 0);
    LGKM0;
    barrier_fence();                 // all waves' frags in regs -> slot free
    if (t < 14) stage(tb, 0, t + 2);
    mfma32();
    // ---- phase h=1: younger = (t+1,0),(t+1,1),(t+2,0) | (15,0),(15,1) | none
    if (t < 14) VMWAIT(12); else if (t == 14) VMWAIT(8); else VMWAIT(0);
    barrier_fence();
    load_frags(tb, 1);
    LGKM0;
    barrier_fence();
    if (t < 14) stage(tb, 1, t + 2);
    mfma32();
  }
  __syncthreads();

  // u16 epilogue: counts tile -> LDS, then coalesced 16B streams to global
  unsigned short* Ct = (unsigned short*)smem;
  #pragma unroll
  for (int m = 0; m < 8; ++m)
    #pragma unroll
    for (int n = 0; n < 4; ++n){
      int lr = wr*128 + m*16 + fq*4;
      int lc = wc*64 + n*16 + fr;
      #pragma unroll
      for (int j = 0; j < 4; ++j)
        Ct[(lr + j)*256 + lc] = (unsigned short)acc[m][n][j];
    }
  __syncthreads();
  #pragma unroll
  for (int q = 0; q < 16; ++q){
    int idx = q*8192 + tid*16;   // byte offset into the 128 KB tile
    int lr = idx >> 9;           // 512 B per local row
    int lcb = idx & 511;
    char* gp = (char*)(out + ((size_t)(brow + lr))*N_DIM + bcol) + lcb;
    *(uint4*)gp = *(const uint4*)&smem[idx];
  }
}

// ---------------- 2-phase 256^2 gemm (mid-ws float path, round-4 verified) --
template<typename OUT_T>
__global__ __launch_bounds__(512, 2) void gemm2_kernel(const unsigned char* __restrict__ A8,
                                                       const unsigned char* __restrict__ B8,
                                                       OUT_T* __restrict__ out){
  __shared__ unsigned char smem[131072];
  int tid = threadIdx.x;
  int lane = tid & 63, w = tid >> 6;
  unsigned bid = blockIdx.x;
  unsigned sw = (bid & 7u)*64u + (bid >> 3);
  int bn = sw & 15, bm = sw >> 4;
  int brow = bm*256, bcol = bn*256;
  int wr = w >> 2, wc = w & 3;
  int fr = lane & 15, fq = lane >> 4;
  int l8 = lane >> 3, slot = lane & 7;

  i32x4 acc[8][4];
  #pragma unroll
  for (int m = 0; m < 8; ++m)
    #pragma unroll
    for (int n = 0; n < 4; ++n) acc[m][n] = (i32x4){0,0,0,0};

  auto stage = [&](int c, int kt){
    unsigned char* As = smem + c*32768;
    unsigned char* Bs = smem + 65536 + c*32768;
    int kk = kt*128;
    #pragma unroll
    for (int q = 0; q < 4; ++q){
      int row = q*64 + w*8 + l8;
      int kb = slot ^ (row & 7);
      gload16(A8 + ((size_t)(brow+row))*K_DIM + kk + kb*16, As + q*8192 + w*1024);
      gload16(B8 + ((size_t)(bcol+row))*K_DIM + kk + kb*16, Bs + q*8192 + w*1024);
    }
  };

  stage(0, 0);
  __syncthreads();
  int cur = 0;
  for (int kt = 0; kt < 16; ++kt){
    if (kt < 15) stage(cur ^ 1, kt + 1);
    const unsigned char* As = smem + cur*32768;
    const unsigned char* Bs = smem + 65536 + cur*32768;
    #pragma unroll
    for (int ks = 0; ks < 2; ++ks){
      i32x4 b[4];
      #pragma unroll
      for (int n = 0; n < 4; ++n){
        int row = wc*64 + n*16 + fr;
        int sl = (ks*4 + fq) ^ (row & 7);
        b[n] = *(const i32x4*)&Bs[row*128 + sl*16];
      }
      #pragma unroll
      for (int mh = 0; mh < 2; ++mh){
        i32x4 a[4];
        #pragma unroll
        for (int mi = 0; mi < 4; ++mi){
          int row = wr*128 + (mh*4 + mi)*16 + fr;
          int sl = (ks*4 + fq) ^ (row & 7);
          a[mi] = *(const i32x4*)&As[row*128 + sl*16];
        }
        #pragma unroll
        for (int mi = 0; mi < 4; ++mi)
          #pragma unroll
          for (int n = 0; n < 4; ++n)
            acc[mh*4+mi][n] = __builtin_amdgcn_mfma_i32_16x16x64_i8(
                a[mi], b[n], acc[mh*4+mi][n], 0, 0, 0);
      }
    }
    __syncthreads();
    cur ^= 1;
  }
  #pragma unroll
  for (int m = 0; m < 8; ++m)
    #pragma unroll
    for (int n = 0; n < 4; ++n){
      int row = brow + wr*128 + m*16 + fq*4;
      int col = bcol + wc*64 + n*16 + fr;
      #pragma unroll
      for (int j = 0; j < 4; ++j)
        out[((size_t)(row + j))*N_DIM + col] = (OUT_T)acc[m][n][j];
    }
}

// ---------------- fallback GEMM (tiny ws): bf16 reg-staged ------------------
__global__ __launch_bounds__(256) void gemm_fb_kernel(const float* __restrict__ X,
                                                      const float* __restrict__ Cn,
                                                      float* __restrict__ out){
  __shared__ ushort_t As[128*32];
  __shared__ ushort_t Bs[128*32];
  int tid = threadIdx.x;
  int bn = blockIdx.x & 31, bm = blockIdx.x >> 5;
  int brow = bm * 128, bcol = bn * 128;
  int lane = tid & 63, w = tid >> 6;
  int wr = w >> 1, wc = w & 1;
  int fr = lane & 15, fq = lane >> 4;
  f32x4 acc[4][4];
  for (int m = 0; m < 4; ++m)
    for (int n = 0; n < 4; ++n)
      acc[m][n] = (f32x4){0.f, 0.f, 0.f, 0.f};
  int r2 = tid >> 1, h = tid & 1;
  int kr = tid >> 3, seg = tid & 7;
  for (int kk = 0; kk < K_DIM; kk += 32){
    __syncthreads();
    const float* ga = X + ((size_t)(brow + r2))*K_DIM + kk + h*16;
    unsigned pk[8];
    for (int q = 0; q < 4; ++q){
      float4 f = *(const float4*)(ga + q*4);
      pk[q*2]   = (unsigned)f2bf(f.x) | ((unsigned)f2bf(f.y) << 16);
      pk[q*2+1] = (unsigned)f2bf(f.z) | ((unsigned)f2bf(f.w) << 16);
    }
    uint4 u0; u0.x = pk[0]; u0.y = pk[1]; u0.z = pk[2]; u0.w = pk[3];
    uint4 u1; u1.x = pk[4]; u1.y = pk[5]; u1.z = pk[6]; u1.w = pk[7];
    *(uint4*)&As[r2*32 + h*16]     = u0;
    *(uint4*)&As[r2*32 + h*16 + 8] = u1;
    const float* gb = Cn + ((size_t)(kk + kr))*N_DIM + bcol + seg*16;
    for (int q = 0; q < 4; ++q){
      float4 f = *(const float4*)(gb + q*4);
      Bs[(seg*16 + q*4 + 0)*32 + kr] = f2bf(f.x);
      Bs[(seg*16 + q*4 + 1)*32 + kr] = f2bf(f.y);
      Bs[(seg*16 + q*4 + 2)*32 + kr] = f2bf(f.z);
      Bs[(seg*16 + q*4 + 3)*32 + kr] = f2bf(f.w);
    }
    __syncthreads();
    short8 a[4], b[4];
    for (int m = 0; m < 4; ++m) a[m] = *(const short8*)&As[(wr*64 + m*16 + fr)*32 + fq*8];
    for (int n = 0; n < 4; ++n) b[n] = *(const short8*)&Bs[(wc*64 + n*16 + fr)*32 + fq*8];
    for (int m = 0; m < 4; ++m)
      for (int n = 0; n < 4; ++n)
        acc[m][n] = __builtin_amdgcn_mfma_f32_16x16x32_bf16(a[m], b[n], acc[m][n], 0, 0, 0);
  }
  for (int m = 0; m < 4; ++m)
    for (int n = 0; n < 4; ++n){
      int row = brow + wr*64 + m*16 + fq*4;
      int col = bcol + wc*64 + n*16 + fr;
      for (int j = 0; j < 4; ++j)
        out[((size_t)(row + j))*N_DIM + col] = acc[m][n][j];
    }
}

// ---------------- per-row exact top-82 -> one-hot ---------------------------
// Two-level radix select on the DOUBLE bit pattern (positive doubles: value
// order == u64 bit order). Tie-break: lower index wins.
__device__ __forceinline__ void find_bin(unsigned* hist, unsigned* wtot,
                                         int* pB, int* pK, int tid, int Kt){
  int lane = tid & 63, w = tid >> 6;
  unsigned s = 0;
  #pragma unroll
  for (int b = 0; b < 16; ++b) s += hist[tid*16 + b];
  unsigned S = s;
  #pragma unroll
  for (int off = 1; off < 64; off <<= 1){
    unsigned T = __shfl_down(S, off, 64);
    if (lane + off < 64) S += T;
  }
  if (lane == 0) wtot[w] = S;          // whole-wave total (suffix at lane 0)
  __syncthreads();
  unsigned above = 0;
  for (int w2 = w + 1; w2 < 4; ++w2) above += wtot[w2];
  unsigned St = S + above;             // count with bin >= tid*16
  unsigned Sn = St - s;                // count with bin >= (tid+1)*16
  if (St >= (unsigned)Kt && Sn < (unsigned)Kt){   // exactly one thread
    unsigned cum = Sn;
    for (int b = 15; b >= 0; --b){
      unsigned hb = hist[tid*16 + b];
      cum += hb;
      if (cum >= (unsigned)Kt){ *pB = tid*16 + b; *pK = Kt - (int)(cum - hb); break; }
    }
  }
  __syncthreads();
}

template<typename CT>
__global__ __launch_bounds__(256) void topk_kernel(const CT* __restrict__ cnt,
                                                   float* __restrict__ outp,
                                                   const double* __restrict__ boost){
  __shared__ unsigned hist[4096];
  __shared__ unsigned wtot[4];
  __shared__ int sB, sK, sB2, sK2, scnt, sTi;
  __shared__ u64 sTv;
  __shared__ u64 cbits[256];
  __shared__ int cidx[256];
  int tid = threadIdx.x;
  const CT* rp = cnt + (size_t)blockIdx.x * N_DIM;
  float* wp = outp + (size_t)blockIdx.x * N_DIM;

  double v[16];
  unsigned bin[16];
  #pragma unroll
  for (int g = 0; g < 4; ++g){
    int c0 = g*1024 + tid*4;
    double4 bf = *(const double4*)&boost[c0];
    if constexpr (sizeof(CT) == 2){
      ushort4 f = *(const ushort4*)&rp[c0];
      v[g*4+0] = (double)f.x * bf.x;
      v[g*4+1] = (double)f.y * bf.y;
      v[g*4+2] = (double)f.z * bf.z;
      v[g*4+3] = (double)f.w * bf.w;
    } else {
      float4 f = *(const float4*)&rp[c0];
      v[g*4+0] = (double)f.x * bf.x;
      v[g*4+1] = (double)f.y * bf.y;
      v[g*4+2] = (double)f.z * bf.z;
      v[g*4+3] = (double)f.w * bf.w;
    }
  }
  #pragma unroll
  for (int e = 0; e < 16; ++e)
    bin[e] = (unsigned)(((u64)__double_as_longlong(v[e])) >> 51) & 4095u;

  #pragma unroll
  for (int i = 0; i < 16; ++i) hist[tid + 256*i] = 0u;
  __syncthreads();
  #pragma unroll
  for (int e = 0; e < 16; ++e) atomicAdd(&hist[bin[e]], 1u);
  __syncthreads();

  find_bin(hist, wtot, &sB, &sK, tid, TOPK);       // L1: boundary bin B, rank k1
  int B = sB, k1 = sK;

  #pragma unroll
  for (int i = 0; i < 16; ++i) hist[tid + 256*i] = 0u;
  if (tid == 0) scnt = 0;
  __syncthreads();
  #pragma unroll
  for (int e = 0; e < 16; ++e){
    if (bin[e] == (unsigned)B){
      unsigned b2 = (unsigned)(((u64)__double_as_longlong(v[e])) >> 39) & 4095u;
      atomicAdd(&hist[b2], 1u);
    }
  }
  __syncthreads();

  find_bin(hist, wtot, &sB2, &sK2, tid, k1);       // L2: sub-bin B2, rank k2
  int B2 = sB2, k2 = sK2;

  #pragma unroll
  for (int e = 0; e < 16; ++e){
    if (bin[e] == (unsigned)B){
      u64 ub = (u64)__double_as_longlong(v[e]);
      if ((unsigned)((ub >> 39) & 4095u) == (unsigned)B2){
        int pos = atomicAdd(&scnt, 1);
        if (pos < 256){
          int g = e >> 2, j = e & 3;
          cbits[pos] = ub;
          cidx[pos] = g*1024 + tid*4 + j;
        }
      }
    }
  }
  __syncthreads();
  int Csz = scnt; if (Csz > 256) Csz = 256;
  for (int i = tid; i < Csz; i += 256){
    u64 bi = cbits[i]; int xi = cidx[i];
    int rk = 0;
    for (int j2 = 0; j2 < Csz; ++j2){
      u64 bj = cbits[j2];
      rk += (int)((bj > bi) || (bj == bi && cidx[j2] < xi));
    }
    if (rk == k2 - 1){ sTv = bi; sTi = xi; }       // the exact K-th element
  }
  __syncthreads();
  double Tv = __longlong_as_double((long long)sTv);
  int Ti = sTi;
  #pragma unroll
  for (int g = 0; g < 4; ++g){
    int c0 = g*1024 + tid*4;
    float4 o;
    o.x = (v[g*4+0] > Tv || (v[g*4+0] == Tv && (c0+0) <= Ti)) ? 1.0f : 0.0f;
    o.y = (v[g*4+1] > Tv || (v[g*4+1] == Tv && (c0+1) <= Ti)) ? 1.0f : 0.0f;
    o.z = (v[g*4+2] > Tv || (v[g*4+2] == Tv && (c0+2) <= Ti)) ? 1.0f : 0.0f;
    o.w = (v[g*4+3] > Tv || (v[g*4+3] == Tv && (c0+3) <= Ti)) ? 1.0f : 0.0f;
    *(float4*)&wp[c0] = o;
  }
}

extern "C" void kernel_launch(void* const* d_in, const int* in_sizes, int n_in,
                              void* d_out, int out_size, void* d_ws, size_t ws_size,
                              hipStream_t stream){
  (void)in_sizes; (void)n_in; (void)out_size;
  const float* X   = (const float*)d_in[0];   // x [8192][2048]
  const float* Cn  = (const float*)d_in[1];   // connection [2048][4096]
  const float* avg = (const float*)d_in[2];   // avg_activation [4096]
  float* out = (float*)d_out;                 // [8192][4096]
  char* ws = (char*)d_ws;

  double* boost = (double*)ws;                                          // 32 KB
  const size_t offA = 65536;
  unsigned char* A8 = (unsigned char*)(ws + offA);                      // 16 MB
  unsigned char* B8 = (unsigned char*)(ws + offA + (size_t)16777216);   //  8 MB
  unsigned short* CNT = (unsigned short*)(ws + offA + (size_t)25165824);// 64 MB
  const size_t need_mid  = offA + (size_t)25165824;
  const size_t need_full = need_mid + (size_t)67108864;

  boost_kernel<<<dim3(1), dim3(256), 0, stream>>>(avg, boost);
  if (ws_size >= need_full){
    convA8_kernel<<<dim3(4096), dim3(256), 0, stream>>>(X, A8);
    convB8_kernel<<<dim3(8192), dim3(256), 0, stream>>>(Cn, B8);
    gemm3_kernel<<<dim3(512), dim3(512), 0, stream>>>(A8, B8, CNT);
    topk_kernel<unsigned short><<<dim3(8192), dim3(256), 0, stream>>>(CNT, out, boost);
  } else if (ws_size >= need_mid){
    convA8_kernel<<<dim3(4096), dim3(256), 0, stream>>>(X, A8);
    convB8_kernel<<<dim3(8192), dim3(256), 0, stream>>>(Cn, B8);
    gemm2_kernel<float><<<dim3(512), dim3(512), 0, stream>>>(A8, B8, out);
    topk_kernel<float><<<dim3(8192), dim3(256), 0, stream>>>(out, out, boost);
  } else {
    gemm_fb_kernel<<<dim3(2048), dim3(256), 0, stream>>>(X, Cn, out);
    topk_kernel<float><<<dim3(8192), dim3(256), 0, stream>>>(out, out, boost);
  }
}

// Round 7
// 170.784 us; speedup vs baseline: 1.1185x; 1.0570x over previous
//
#include <hip/hip_runtime.h>
#include <math.h>

#define M_DIM 8192
#define K_DIM 2048
#define N_DIM 4096
#define TOPK  82

typedef short short8 __attribute__((ext_vector_type(8)));
typedef float f32x4 __attribute__((ext_vector_type(4)));
typedef int   i32x4 __attribute__((ext_vector_type(4)));
typedef unsigned short ushort_t;
typedef unsigned long long u64;

__device__ __forceinline__ unsigned short f2bf(float f){
  unsigned u = __float_as_uint(f);
  unsigned r = (u + 0x7FFFu + ((u >> 16) & 1u)) >> 16;  // RNE; exact for 0.0/1.0
  return (unsigned short)r;
}

// async global->LDS, 16B per lane. LDS dest = wave-uniform base + lane*16.
__device__ __forceinline__ void gload16(const void* g, void* l){
  __builtin_amdgcn_global_load_lds(
      (const __attribute__((address_space(1))) unsigned int*)g,
      (__attribute__((address_space(3))) unsigned int*)l,
      16, 0, 0);
}

// ---------------- boost factor (fp64, once) ----------------
__global__ __launch_bounds__(256) void boost_kernel(const float* __restrict__ avg,
                                                    double* __restrict__ boost){
  __shared__ double sp[4];
  __shared__ double stot;
  int tid = threadIdx.x;
  int lane = tid & 63, w = tid >> 6;
  double s = 0.0;
  for (int i = 0; i < 16; ++i) s += (double)avg[tid + 256*i];
  for (int off = 32; off > 0; off >>= 1) s += __shfl_down(s, off, 64);
  if (lane == 0) sp[w] = s;
  __syncthreads();
  if (tid == 0) stot = sp[0] + sp[1] + sp[2] + sp[3];
  __syncthreads();
  double tot = stot;
  for (int i = 0; i < 16; ++i){
    int j = tid + 256*i;
    double a = (double)avg[j];
    double nb = (tot - a) / 4095.0;               // (total - avg)/(D-1)
    boost[j] = exp(-100.0 * (a - nb));
  }
}

// ---------------- A: fp32 -> i8 (binary), layout preserved [M][K] ----------
__global__ __launch_bounds__(256) void convA8_kernel(const float* __restrict__ X,
                                                     unsigned char* __restrict__ A8){
  size_t base = ((size_t)blockIdx.x * 256 + threadIdx.x) * 16;
  unsigned r[4];
  for (int q = 0; q < 4; ++q){
    float4 f = *(const float4*)&X[base + q*4];
    r[q] = (unsigned)(f.x != 0.f) | ((unsigned)(f.y != 0.f) << 8)
         | ((unsigned)(f.z != 0.f) << 16) | ((unsigned)(f.w != 0.f) << 24);
  }
  uint4 o; o.x = r[0]; o.y = r[1]; o.z = r[2]; o.w = r[3];
  *(uint4*)&A8[base] = o;
}

// ---------------- B: fp32 [K][N] -> u8 transposed [N][K] (v2) ---------------
// 128x128 tiles, 512 blocks. float4 reads (16B/lane, dense), LDS f32 staging
// [128][132] (pad 4 words). Column reads: bank = (4*(k0+idx)+n) mod 32 and
// 4*k0 == 0 mod 32, so 32 distinct n cover all 32 banks -> conflict-free.
// Binary test: bits>>23 & 1 (exact for {0.0f, 1.0f}). uint4 packed writes:
// 8 dense 128B row-segments per wave-instr.
__global__ __launch_bounds__(256) void convB8_kernel(const float* __restrict__ Cn,
                                                     unsigned char* __restrict__ B8){
  __shared__ float s[128*132];
  int tid = threadIdx.x;
  int bk = blockIdx.x & 15;        // K/128 = 16 tiles
  int bn = blockIdx.x >> 4;        // N/128 = 32 tiles
  int rr = tid >> 5, cc = (tid & 31)*4;
  #pragma unroll
  for (int p = 0; p < 16; ++p){
    int r = p*8 + rr;
    float4 f = *(const float4*)&Cn[((size_t)(bk*128 + r))*N_DIM + bn*128 + cc];
    *(float4*)&s[r*132 + cc] = f;
  }
  __syncthreads();
  int nn = tid >> 3, k0 = (tid & 7)*16;
  #pragma unroll
  for (int p = 0; p < 4; ++p){
    int n = p*32 + nn;
    unsigned bout[4];
    #pragma unroll
    for (int h = 0; h < 4; ++h){
      unsigned b = 0;
      #pragma unroll
      for (int j = 0; j < 4; ++j){
        unsigned bits = __float_as_uint(s[(k0 + h*4 + j)*132 + n]);
        b |= ((bits >> 23) & 1u) << (8*j);
      }
      bout[h] = b;
    }
    uint4 o; o.x = bout[0]; o.y = bout[1]; o.z = bout[2]; o.w = bout[3];
    *(uint4*)&B8[((size_t)(bn*128 + n))*K_DIM + bk*128 + k0] = o;
  }
}

// ---------------- i8 GEMM, 256x256 tile, 2-phase double-buffered ------------
// (round-4 verified kernel, restored) BK=128, 8 waves, mfma_i32_16x16x64_i8.
// STAGE(next, buf^1) issued before compute; one vmcnt(0)+barrier per K-tile.
// 8-slot XOR swizzle: linear gload_lds dest + inverse-swizzled global source
// + swizzled ds_read (rule #21). u16 epilogue stages counts tile in LDS for
// coalesced 16B stores.
template<typename OUT_T>
__global__ __launch_bounds__(512, 2) void gemm2_kernel(const unsigned char* __restrict__ A8,
                                                       const unsigned char* __restrict__ B8,
                                                       OUT_T* __restrict__ out){
  __shared__ unsigned char smem[131072];
  int tid = threadIdx.x;
  int lane = tid & 63, w = tid >> 6;
  unsigned bid = blockIdx.x;
  unsigned sw = (bid & 7u)*64u + (bid >> 3);   // XCD swizzle, 512%8==0 bijective
  int bn = sw & 15, bm = sw >> 4;
  int brow = bm*256, bcol = bn*256;
  int wr = w >> 2, wc = w & 3;
  int fr = lane & 15, fq = lane >> 4;
  int l8 = lane >> 3, slot = lane & 7;

  i32x4 acc[8][4];
  #pragma unroll
  for (int m = 0; m < 8; ++m)
    #pragma unroll
    for (int n = 0; n < 4; ++n) acc[m][n] = (i32x4){0,0,0,0};

  auto stage = [&](int c, int kt){
    unsigned char* As = smem + c*32768;
    unsigned char* Bs = smem + 65536 + c*32768;
    int kk = kt*128;
    #pragma unroll
    for (int q = 0; q < 4; ++q){
      int row = q*64 + w*8 + l8;
      int kb = slot ^ (row & 7);
      gload16(A8 + ((size_t)(brow+row))*K_DIM + kk + kb*16, As + q*8192 + w*1024);
      gload16(B8 + ((size_t)(bcol+row))*K_DIM + kk + kb*16, Bs + q*8192 + w*1024);
    }
  };

  stage(0, 0);
  __syncthreads();
  int cur = 0;
  for (int kt = 0; kt < 16; ++kt){
    if (kt < 15) stage(cur ^ 1, kt + 1);
    const unsigned char* As = smem + cur*32768;
    const unsigned char* Bs = smem + 65536 + cur*32768;
    #pragma unroll
    for (int ks = 0; ks < 2; ++ks){
      i32x4 b[4];
      #pragma unroll
      for (int n = 0; n < 4; ++n){
        int row = wc*64 + n*16 + fr;
        int sl = (ks*4 + fq) ^ (row & 7);
        b[n] = *(const i32x4*)&Bs[row*128 + sl*16];
      }
      #pragma unroll
      for (int mh = 0; mh < 2; ++mh){
        i32x4 a[4];
        #pragma unroll
        for (int mi = 0; mi < 4; ++mi){
          int row = wr*128 + (mh*4 + mi)*16 + fr;
          int sl = (ks*4 + fq) ^ (row & 7);
          a[mi] = *(const i32x4*)&As[row*128 + sl*16];
        }
        #pragma unroll
        for (int mi = 0; mi < 4; ++mi)
          #pragma unroll
          for (int n = 0; n < 4; ++n)
            acc[mh*4+mi][n] = __builtin_amdgcn_mfma_i32_16x16x64_i8(
                a[mi], b[n], acc[mh*4+mi][n], 0, 0, 0);
      }
    }
    __syncthreads();
    cur ^= 1;
  }

  if constexpr (sizeof(OUT_T) == 2){
    // counts tile -> LDS (scatter), then coalesced 16B streams to global
    unsigned short* Ct = (unsigned short*)smem;
    #pragma unroll
    for (int m = 0; m < 8; ++m)
      #pragma unroll
      for (int n = 0; n < 4; ++n){
        int lr = wr*128 + m*16 + fq*4;
        int lc = wc*64 + n*16 + fr;
        #pragma unroll
        for (int j = 0; j < 4; ++j)
          Ct[(lr + j)*256 + lc] = (unsigned short)acc[m][n][j];
      }
    __syncthreads();
    #pragma unroll
    for (int q = 0; q < 16; ++q){
      int idx = q*8192 + tid*16;   // byte offset into the 128 KB tile
      int lr = idx >> 9;           // 512 B per local row
      int lcb = idx & 511;
      char* gp = (char*)(out + ((size_t)(brow + lr))*N_DIM + bcol) + lcb;
      *(uint4*)gp = *(const uint4*)&smem[idx];
    }
  } else {
    #pragma unroll
    for (int m = 0; m < 8; ++m)
      #pragma unroll
      for (int n = 0; n < 4; ++n){
        int row = brow + wr*128 + m*16 + fq*4;
        int col = bcol + wc*64 + n*16 + fr;
        #pragma unroll
        for (int j = 0; j < 4; ++j)
          out[((size_t)(row + j))*N_DIM + col] = (OUT_T)acc[m][n][j];
      }
  }
}

// ---------------- fallback GEMM (tiny ws): bf16 reg-staged ------------------
__global__ __launch_bounds__(256) void gemm_fb_kernel(const float* __restrict__ X,
                                                      const float* __restrict__ Cn,
                                                      float* __restrict__ out){
  __shared__ ushort_t As[128*32];
  __shared__ ushort_t Bs[128*32];
  int tid = threadIdx.x;
  int bn = blockIdx.x & 31, bm = blockIdx.x >> 5;
  int brow = bm * 128, bcol = bn * 128;
  int lane = tid & 63, w = tid >> 6;
  int wr = w >> 1, wc = w & 1;
  int fr = lane & 15, fq = lane >> 4;
  f32x4 acc[4][4];
  for (int m = 0; m < 4; ++m)
    for (int n = 0; n < 4; ++n)
      acc[m][n] = (f32x4){0.f, 0.f, 0.f, 0.f};
  int r2 = tid >> 1, h = tid & 1;
  int kr = tid >> 3, seg = tid & 7;
  for (int kk = 0; kk < K_DIM; kk += 32){
    __syncthreads();
    const float* ga = X + ((size_t)(brow + r2))*K_DIM + kk + h*16;
    unsigned pk[8];
    for (int q = 0; q < 4; ++q){
      float4 f = *(const float4*)(ga + q*4);
      pk[q*2]   = (unsigned)f2bf(f.x) | ((unsigned)f2bf(f.y) << 16);
      pk[q*2+1] = (unsigned)f2bf(f.z) | ((unsigned)f2bf(f.w) << 16);
    }
    uint4 u0; u0.x = pk[0]; u0.y = pk[1]; u0.z = pk[2]; u0.w = pk[3];
    uint4 u1; u1.x = pk[4]; u1.y = pk[5]; u1.z = pk[6]; u1.w = pk[7];
    *(uint4*)&As[r2*32 + h*16]     = u0;
    *(uint4*)&As[r2*32 + h*16 + 8] = u1;
    const float* gb = Cn + ((size_t)(kk + kr))*N_DIM + bcol + seg*16;
    for (int q = 0; q < 4; ++q){
      float4 f = *(const float4*)(gb + q*4);
      Bs[(seg*16 + q*4 + 0)*32 + kr] = f2bf(f.x);
      Bs[(seg*16 + q*4 + 1)*32 + kr] = f2bf(f.y);
      Bs[(seg*16 + q*4 + 2)*32 + kr] = f2bf(f.z);
      Bs[(seg*16 + q*4 + 3)*32 + kr] = f2bf(f.w);
    }
    __syncthreads();
    short8 a[4], b[4];
    for (int m = 0; m < 4; ++m) a[m] = *(const short8*)&As[(wr*64 + m*16 + fr)*32 + fq*8];
    for (int n = 0; n < 4; ++n) b[n] = *(const short8*)&Bs[(wc*64 + n*16 + fr)*32 + fq*8];
    for (int m = 0; m < 4; ++m)
      for (int n = 0; n < 4; ++n)
        acc[m][n] = __builtin_amdgcn_mfma_f32_16x16x32_bf16(a[m], b[n], acc[m][n], 0, 0, 0);
  }
  for (int m = 0; m < 4; ++m)
    for (int n = 0; n < 4; ++n){
      int row = brow + wr*64 + m*16 + fq*4;
      int col = bcol + wc*64 + n*16 + fr;
      for (int j = 0; j < 4; ++j)
        out[((size_t)(row + j))*N_DIM + col] = acc[m][n][j];
    }
}

// ---------------- per-row exact top-82 -> one-hot ---------------------------
// Two-level radix select on the DOUBLE bit pattern (positive doubles: value
// order == u64 bit order). Tie-break: lower index wins.
__device__ __forceinline__ void find_bin(unsigned* hist, unsigned* wtot,
                                         int* pB, int* pK, int tid, int Kt){
  int lane = tid & 63, w = tid >> 6;
  unsigned s = 0;
  #pragma unroll
  for (int b = 0; b < 16; ++b) s += hist[tid*16 + b];
  unsigned S = s;
  #pragma unroll
  for (int off = 1; off < 64; off <<= 1){
    unsigned T = __shfl_down(S, off, 64);
    if (lane + off < 64) S += T;
  }
  if (lane == 0) wtot[w] = S;          // whole-wave total (suffix at lane 0)
  __syncthreads();
  unsigned above = 0;
  for (int w2 = w + 1; w2 < 4; ++w2) above += wtot[w2];
  unsigned St = S + above;             // count with bin >= tid*16
  unsigned Sn = St - s;                // count with bin >= (tid+1)*16
  if (St >= (unsigned)Kt && Sn < (unsigned)Kt){   // exactly one thread
    unsigned cum = Sn;
    for (int b = 15; b >= 0; --b){
      unsigned hb = hist[tid*16 + b];
      cum += hb;
      if (cum >= (unsigned)Kt){ *pB = tid*16 + b; *pK = Kt - (int)(cum - hb); break; }
    }
  }
  __syncthreads();
}

template<typename CT>
__global__ __launch_bounds__(256) void topk_kernel(const CT* __restrict__ cnt,
                                                   float* __restrict__ outp,
                                                   const double* __restrict__ boost){
  __shared__ unsigned hist[4096];
  __shared__ unsigned wtot[4];
  __shared__ int sB, sK, sB2, sK2, scnt, sTi;
  __shared__ u64 sTv;
  __shared__ u64 cbits[256];
  __shared__ int cidx[256];
  int tid = threadIdx.x;
  const CT* rp = cnt + (size_t)blockIdx.x * N_DIM;
  float* wp = outp + (size_t)blockIdx.x * N_DIM;

  double v[16];
  unsigned bin[16];
  #pragma unroll
  for (int g = 0; g < 4; ++g){
    int c0 = g*1024 + tid*4;
    double4 bf = *(const double4*)&boost[c0];
    if constexpr (sizeof(CT) == 2){
      ushort4 f = *(const ushort4*)&rp[c0];
      v[g*4+0] = (double)f.x * bf.x;
      v[g*4+1] = (double)f.y * bf.y;
      v[g*4+2] = (double)f.z * bf.z;
      v[g*4+3] = (double)f.w * bf.w;
    } else {
      float4 f = *(const float4*)&rp[c0];
      v[g*4+0] = (double)f.x * bf.x;
      v[g*4+1] = (double)f.y * bf.y;
      v[g*4+2] = (double)f.z * bf.z;
      v[g*4+3] = (double)f.w * bf.w;
    }
  }
  #pragma unroll
  for (int e = 0; e < 16; ++e)
    bin[e] = (unsigned)(((u64)__double_as_longlong(v[e])) >> 51) & 4095u;

  #pragma unroll
  for (int i = 0; i < 16; ++i) hist[tid + 256*i] = 0u;
  __syncthreads();
  #pragma unroll
  for (int e = 0; e < 16; ++e) atomicAdd(&hist[bin[e]], 1u);
  __syncthreads();

  find_bin(hist, wtot, &sB, &sK, tid, TOPK);       // L1: boundary bin B, rank k1
  int B = sB, k1 = sK;

  #pragma unroll
  for (int i = 0; i < 16; ++i) hist[tid + 256*i] = 0u;
  if (tid == 0) scnt = 0;
  __syncthreads();
  #pragma unroll
  for (int e = 0; e < 16; ++e){
    if (bin[e] == (unsigned)B){
      unsigned b2 = (unsigned)(((u64)__double_as_longlong(v[e])) >> 39) & 4095u;
      atomicAdd(&hist[b2], 1u);
    }
  }
  __syncthreads();

  find_bin(hist, wtot, &sB2, &sK2, tid, k1);       // L2: sub-bin B2, rank k2
  int B2 = sB2, k2 = sK2;

  #pragma unroll
  for (int e = 0; e < 16; ++e){
    if (bin[e] == (unsigned)B){
      u64 ub = (u64)__double_as_longlong(v[e]);
      if ((unsigned)((ub >> 39) & 4095u) == (unsigned)B2){
        int pos = atomicAdd(&scnt, 1);
        if (pos < 256){
          int g = e >> 2, j = e & 3;
          cbits[pos] = ub;
          cidx[pos] = g*1024 + tid*4 + j;
        }
      }
    }
  }
  __syncthreads();
  int Csz = scnt; if (Csz > 256) Csz = 256;
  for (int i = tid; i < Csz; i += 256){
    u64 bi = cbits[i]; int xi = cidx[i];
    int rk = 0;
    for (int j2 = 0; j2 < Csz; ++j2){
      u64 bj = cbits[j2];
      rk += (int)((bj > bi) || (bj == bi && cidx[j2] < xi));
    }
    if (rk == k2 - 1){ sTv = bi; sTi = xi; }       // the exact K-th element
  }
  __syncthreads();
  double Tv = __longlong_as_double((long long)sTv);
  int Ti = sTi;
  #pragma unroll
  for (int g = 0; g < 4; ++g){
    int c0 = g*1024 + tid*4;
    float4 o;
    o.x = (v[g*4+0] > Tv || (v[g*4+0] == Tv && (c0+0) <= Ti)) ? 1.0f : 0.0f;
    o.y = (v[g*4+1] > Tv || (v[g*4+1] == Tv && (c0+1) <= Ti)) ? 1.0f : 0.0f;
    o.z = (v[g*4+2] > Tv || (v[g*4+2] == Tv && (c0+2) <= Ti)) ? 1.0f : 0.0f;
    o.w = (v[g*4+3] > Tv || (v[g*4+3] == Tv && (c0+3) <= Ti)) ? 1.0f : 0.0f;
    *(float4*)&wp[c0] = o;
  }
}

extern "C" void kernel_launch(void* const* d_in, const int* in_sizes, int n_in,
                              void* d_out, int out_size, void* d_ws, size_t ws_size,
                              hipStream_t stream){
  (void)in_sizes; (void)n_in; (void)out_size;
  const float* X   = (const float*)d_in[0];   // x [8192][2048]
  const float* Cn  = (const float*)d_in[1];   // connection [2048][4096]
  const float* avg = (const float*)d_in[2];   // avg_activation [4096]
  float* out = (float*)d_out;                 // [8192][4096]
  char* ws = (char*)d_ws;

  double* boost = (double*)ws;                                          // 32 KB
  const size_t offA = 65536;
  unsigned char* A8 = (unsigned char*)(ws + offA);                      // 16 MB
  unsigned char* B8 = (unsigned char*)(ws + offA + (size_t)16777216);   //  8 MB
  unsigned short* CNT = (unsigned short*)(ws + offA + (size_t)25165824);// 64 MB
  const size_t need_mid  = offA + (size_t)25165824;
  const size_t need_full = need_mid + (size_t)67108864;

  boost_kernel<<<dim3(1), dim3(256), 0, stream>>>(avg, boost);
  if (ws_size >= need_full){
    convA8_kernel<<<dim3(4096), dim3(256), 0, stream>>>(X, A8);
    convB8_kernel<<<dim3(512), dim3(256), 0, stream>>>(Cn, B8);
    gemm2_kernel<unsigned short><<<dim3(512), dim3(512), 0, stream>>>(A8, B8, CNT);
    topk_kernel<unsigned short><<<dim3(8192), dim3(256), 0, stream>>>(CNT, out, boost);
  } else if (ws_size >= need_mid){
    convA8_kernel<<<dim3(4096), dim3(256), 0, stream>>>(X, A8);
    convB8_kernel<<<dim3(512), dim3(256), 0, stream>>>(Cn, B8);
    gemm2_kernel<float><<<dim3(512), dim3(512), 0, stream>>>(A8, B8, out);
    topk_kernel<float><<<dim3(8192), dim3(256), 0, stream>>>(out, out, boost);
  } else {
    gemm_fb_kernel<<<dim3(2048), dim3(256), 0, stream>>>(X, Cn, out);
    topk_kernel<float><<<dim3(8192), dim3(256), 0, stream>>>(out, out, boost);
  }
}

// Round 8
// 161.390 us; speedup vs baseline: 1.1836x; 1.0582x over previous
//
#include <hip/hip_runtime.h>
#include <math.h>

#define M_DIM 8192
#define K_DIM 2048
#define N_DIM 4096
#define TOPK  82

typedef short short8 __attribute__((ext_vector_type(8)));
typedef float f32x4 __attribute__((ext_vector_type(4)));
typedef int   i32x4 __attribute__((ext_vector_type(4)));
typedef unsigned short ushort_t;
typedef unsigned long long u64;

#define VMWAIT(N) do { asm volatile("s_waitcnt vmcnt(" #N ")" ::: "memory"); \
                       __builtin_amdgcn_sched_barrier(0); } while(0)
#define LGKM0     do { asm volatile("s_waitcnt lgkmcnt(0)" ::: "memory"); \
                       __builtin_amdgcn_sched_barrier(0); } while(0)
__device__ __forceinline__ void barrier_fence(){
  __builtin_amdgcn_s_barrier();
  __builtin_amdgcn_sched_barrier(0);
}

__device__ __forceinline__ unsigned short f2bf(float f){
  unsigned u = __float_as_uint(f);
  unsigned r = (u + 0x7FFFu + ((u >> 16) & 1u)) >> 16;  // RNE; exact for 0.0/1.0
  return (unsigned short)r;
}

// async global->LDS, 16B per lane. LDS dest = wave-uniform base + lane*16.
__device__ __forceinline__ void gload16(const void* g, void* l){
  __builtin_amdgcn_global_load_lds(
      (const __attribute__((address_space(1))) unsigned int*)g,
      (__attribute__((address_space(3))) unsigned int*)l,
      16, 0, 0);
}

// ---------------- fused prep: convA (0..4095) | convB (4096..4607) | boost --
__global__ __launch_bounds__(256) void prep_kernel(const float* __restrict__ X,
                                                   const float* __restrict__ Cn,
                                                   const float* __restrict__ avg,
                                                   unsigned char* __restrict__ A8,
                                                   unsigned char* __restrict__ B8,
                                                   double* __restrict__ boost){
  int bid = blockIdx.x;
  int tid = threadIdx.x;
  if (bid < 4096){
    // A: fp32 -> u8 binary, layout preserved [M][K]
    size_t base = ((size_t)bid * 256 + tid) * 16;
    unsigned r[4];
    #pragma unroll
    for (int q = 0; q < 4; ++q){
      float4 f = *(const float4*)&X[base + q*4];
      r[q] = (unsigned)(f.x != 0.f) | ((unsigned)(f.y != 0.f) << 8)
           | ((unsigned)(f.z != 0.f) << 16) | ((unsigned)(f.w != 0.f) << 24);
    }
    uint4 o; o.x = r[0]; o.y = r[1]; o.z = r[2]; o.w = r[3];
    *(uint4*)&A8[base] = o;
  } else if (bid < 4608){
    // B: fp32 [K][N] -> u8 transposed [N][K], 128x128 tiles
    __shared__ float s[128*132];
    int b = bid - 4096;
    int bk = b & 15, bn = b >> 4;
    int rr = tid >> 5, cc = (tid & 31)*4;
    #pragma unroll
    for (int p = 0; p < 16; ++p){
      int r = p*8 + rr;
      float4 f = *(const float4*)&Cn[((size_t)(bk*128 + r))*N_DIM + bn*128 + cc];
      *(float4*)&s[r*132 + cc] = f;
    }
    __syncthreads();
    int nn = tid >> 3, k0 = (tid & 7)*16;
    #pragma unroll
    for (int p = 0; p < 4; ++p){
      int n = p*32 + nn;
      unsigned bout[4];
      #pragma unroll
      for (int h = 0; h < 4; ++h){
        unsigned bb = 0;
        #pragma unroll
        for (int j = 0; j < 4; ++j){
          unsigned bits = __float_as_uint(s[(k0 + h*4 + j)*132 + n]);
          bb |= ((bits >> 23) & 1u) << (8*j);
        }
        bout[h] = bb;
      }
      uint4 o; o.x = bout[0]; o.y = bout[1]; o.z = bout[2]; o.w = bout[3];
      *(uint4*)&B8[((size_t)(bn*128 + n))*K_DIM + bk*128 + k0] = o;
    }
  } else {
    // boost factor (fp64)
    __shared__ double sp[4];
    __shared__ double stot;
    int lane = tid & 63, w = tid >> 6;
    double s = 0.0;
    for (int i = 0; i < 16; ++i) s += (double)avg[tid + 256*i];
    for (int off = 32; off > 0; off >>= 1) s += __shfl_down(s, off, 64);
    if (lane == 0) sp[w] = s;
    __syncthreads();
    if (tid == 0) stot = sp[0] + sp[1] + sp[2] + sp[3];
    __syncthreads();
    double tot = stot;
    for (int i = 0; i < 16; ++i){
      int j = tid + 256*i;
      double a = (double)avg[j];
      double nb = (tot - a) / 4095.0;
      boost[j] = exp(-100.0 * (a - nb));
    }
  }
}

// ---------------- i8 GEMM, 256x256, depth-2 prefetch ring (T4) --------------
// BK=64, 3 bufs x (16KB A + 16KB B) = 96 KB LDS, 8 waves, 32 K-tiles.
// Per tile: VMWAIT(4) [stage(t) landed, stage(t+1) in flight] -> raw barrier
// -> 12x ds_read_b128 frags -> issue stage(t+2) -> lgkmcnt(0) -> 32 MFMA.
// One barrier per tile; vmcnt never drained to 0 in steady state.
// Paired-row LDS layout (round-6 verified): logical (row r, chunk c in 0..3)
// -> pair=r>>1, slot s=((r&1)*4+c)^(pair&7), byte pair*128+s*16. Fragment
// reads give each bank-quad exactly 8x16B per b128 instr = conflict-free min.
// Staging: linear gload_lds dest + inverse-swizzled global source (rule #21).
__global__ __launch_bounds__(512, 2) void gemm4_kernel(const unsigned char* __restrict__ A8,
                                                       const unsigned char* __restrict__ B8,
                                                       unsigned short* __restrict__ out){
  __shared__ unsigned char smem[98304];   // A: c*16384, B: 49152 + c*16384
  int tid = threadIdx.x;
  int lane = tid & 63, w = tid >> 6;
  unsigned bid = blockIdx.x;
  unsigned sw = (bid & 7u)*64u + (bid >> 3);   // XCD swizzle, 512%8==0 bijective
  int bn = sw & 15, bm = sw >> 4;
  int brow = bm*256, bcol = bn*256;
  int wr = w >> 2, wc = w & 3;
  int fr = lane & 15, fq = lane >> 4;
  // staging decode: lane writes slot s=lane&7 of pair pl=lane>>3 (h=pl&7)
  int pl = lane >> 3;
  int sx = (lane & 7) ^ (pl & 7);
  int sp2 = sx >> 2;                           // source row parity
  int sc = sx & 3;                             // source chunk

  i32x4 acc[8][4];
  #pragma unroll
  for (int m = 0; m < 8; ++m)
    #pragma unroll
    for (int n = 0; n < 4; ++n) acc[m][n] = (i32x4){0,0,0,0};

  auto stage = [&](int c, int kt){
    unsigned char* Ad = smem + c*16384;
    unsigned char* Bd = smem + 49152 + c*16384;
    int kbase = kt*64;
    #pragma unroll
    for (int i = 0; i < 2; ++i){
      int R0 = w*32 + i*16;
      int r  = R0 + 2*pl + sp2;
      gload16(A8 + ((size_t)(brow + r))*K_DIM + kbase + sc*16, Ad + R0*64);
      gload16(B8 + ((size_t)(bcol + r))*K_DIM + kbase + sc*16, Bd + R0*64);
    }
  };

  auto lds_off = [&](int r)->int{
    int pair = r >> 1;
    int s = (((r & 1) << 2) + fq) ^ (pair & 7);
    return pair*128 + s*16;
  };

  stage(0, 0); stage(1, 1);          // 8 outstanding
  int cur = 0;
  for (int t = 0; t < 32; ++t){
    if (t < 31){ VMWAIT(4); } else { VMWAIT(0); }
    barrier_fence();
    const unsigned char* Ah = smem + cur*16384;
    const unsigned char* Bh = smem + 49152 + cur*16384;
    i32x4 a[8], b[4];
    #pragma unroll
    for (int n = 0; n < 4; ++n)
      b[n] = *(const i32x4*)&Bh[lds_off(wc*64 + n*16 + fr)];
    #pragma unroll
    for (int m = 0; m < 8; ++m)
      a[m] = *(const i32x4*)&Ah[lds_off(wr*128 + m*16 + fr)];
    if (t < 30){
      int nb = cur + 2; if (nb >= 3) nb -= 3;
      stage(nb, t + 2);
    }
    LGKM0;
    #pragma unroll
    for (int m = 0; m < 8; ++m)
      #pragma unroll
      for (int n = 0; n < 4; ++n)
        acc[m][n] = __builtin_amdgcn_mfma_i32_16x16x64_i8(a[m], b[n], acc[m][n], 0, 0, 0);
    ++cur; if (cur >= 3) cur = 0;
  }
  __syncthreads();

  // u16 epilogue in two 64 KB passes (96 KB LDS < full 128 KB tile)
  unsigned short* Ct = (unsigned short*)smem;
  #pragma unroll
  for (int p = 0; p < 2; ++p){
    if (wr == p){
      #pragma unroll
      for (int m = 0; m < 8; ++m)
        #pragma unroll
        for (int n = 0; n < 4; ++n){
          int lr = m*16 + fq*4;              // 0..127 within this half
          int lc = wc*64 + n*16 + fr;
          #pragma unroll
          for (int j = 0; j < 4; ++j)
            Ct[(lr + j)*256 + lc] = (unsigned short)acc[m][n][j];
        }
    }
    __syncthreads();
    #pragma unroll
    for (int q = 0; q < 8; ++q){
      int idx = q*8192 + tid*16;             // byte offset into 64 KB half
      int lr = idx >> 9;
      int lcb = idx & 511;
      char* gp = (char*)(out + ((size_t)(brow + p*128 + lr))*N_DIM + bcol) + lcb;
      *(uint4*)gp = *(const uint4*)&smem[idx];
    }
    __syncthreads();
  }
}

// ---------------- 2-phase 256^2 gemm (mid-ws float path, round-4 verified) --
template<typename OUT_T>
__global__ __launch_bounds__(512, 2) void gemm2_kernel(const unsigned char* __restrict__ A8,
                                                       const unsigned char* __restrict__ B8,
                                                       OUT_T* __restrict__ out){
  __shared__ unsigned char smem[131072];
  int tid = threadIdx.x;
  int lane = tid & 63, w = tid >> 6;
  unsigned bid = blockIdx.x;
  unsigned sw = (bid & 7u)*64u + (bid >> 3);
  int bn = sw & 15, bm = sw >> 4;
  int brow = bm*256, bcol = bn*256;
  int wr = w >> 2, wc = w & 3;
  int fr = lane & 15, fq = lane >> 4;
  int l8 = lane >> 3, slot = lane & 7;

  i32x4 acc[8][4];
  #pragma unroll
  for (int m = 0; m < 8; ++m)
    #pragma unroll
    for (int n = 0; n < 4; ++n) acc[m][n] = (i32x4){0,0,0,0};

  auto stage = [&](int c, int kt){
    unsigned char* As = smem + c*32768;
    unsigned char* Bs = smem + 65536 + c*32768;
    int kk = kt*128;
    #pragma unroll
    for (int q = 0; q < 4; ++q){
      int row = q*64 + w*8 + l8;
      int kb = slot ^ (row & 7);
      gload16(A8 + ((size_t)(brow+row))*K_DIM + kk + kb*16, As + q*8192 + w*1024);
      gload16(B8 + ((size_t)(bcol+row))*K_DIM + kk + kb*16, Bs + q*8192 + w*1024);
    }
  };

  stage(0, 0);
  __syncthreads();
  int cur = 0;
  for (int kt = 0; kt < 16; ++kt){
    if (kt < 15) stage(cur ^ 1, kt + 1);
    const unsigned char* As = smem + cur*32768;
    const unsigned char* Bs = smem + 65536 + cur*32768;
    #pragma unroll
    for (int ks = 0; ks < 2; ++ks){
      i32x4 b[4];
      #pragma unroll
      for (int n = 0; n < 4; ++n){
        int row = wc*64 + n*16 + fr;
        int sl = (ks*4 + fq) ^ (row & 7);
        b[n] = *(const i32x4*)&Bs[row*128 + sl*16];
      }
      #pragma unroll
      for (int mh = 0; mh < 2; ++mh){
        i32x4 a[4];
        #pragma unroll
        for (int mi = 0; mi < 4; ++mi){
          int row = wr*128 + (mh*4 + mi)*16 + fr;
          int sl = (ks*4 + fq) ^ (row & 7);
          a[mi] = *(const i32x4*)&As[row*128 + sl*16];
        }
        #pragma unroll
        for (int mi = 0; mi < 4; ++mi)
          #pragma unroll
          for (int n = 0; n < 4; ++n)
            acc[mh*4+mi][n] = __builtin_amdgcn_mfma_i32_16x16x64_i8(
                a[mi], b[n], acc[mh*4+mi][n], 0, 0, 0);
      }
    }
    __syncthreads();
    cur ^= 1;
  }
  #pragma unroll
  for (int m = 0; m < 8; ++m)
    #pragma unroll
    for (int n = 0; n < 4; ++n){
      int row = brow + wr*128 + m*16 + fq*4;
      int col = bcol + wc*64 + n*16 + fr;
      #pragma unroll
      for (int j = 0; j < 4; ++j)
        out[((size_t)(row + j))*N_DIM + col] = (OUT_T)acc[m][n][j];
    }
}

// ---------------- fallback GEMM (tiny ws): bf16 reg-staged ------------------
__global__ __launch_bounds__(256) void gemm_fb_kernel(const float* __restrict__ X,
                                                      const float* __restrict__ Cn,
                                                      float* __restrict__ out){
  __shared__ ushort_t As[128*32];
  __shared__ ushort_t Bs[128*32];
  int tid = threadIdx.x;
  int bn = blockIdx.x & 31, bm = blockIdx.x >> 5;
  int brow = bm * 128, bcol = bn * 128;
  int lane = tid & 63, w = tid >> 6;
  int wr = w >> 1, wc = w & 1;
  int fr = lane & 15, fq = lane >> 4;
  f32x4 acc[4][4];
  for (int m = 0; m < 4; ++m)
    for (int n = 0; n < 4; ++n)
      acc[m][n] = (f32x4){0.f, 0.f, 0.f, 0.f};
  int r2 = tid >> 1, h = tid & 1;
  int kr = tid >> 3, seg = tid & 7;
  for (int kk = 0; kk < K_DIM; kk += 32){
    __syncthreads();
    const float* ga = X + ((size_t)(brow + r2))*K_DIM + kk + h*16;
    unsigned pk[8];
    for (int q = 0; q < 4; ++q){
      float4 f = *(const float4*)(ga + q*4);
      pk[q*2]   = (unsigned)f2bf(f.x) | ((unsigned)f2bf(f.y) << 16);
      pk[q*2+1] = (unsigned)f2bf(f.z) | ((unsigned)f2bf(f.w) << 16);
    }
    uint4 u0; u0.x = pk[0]; u0.y = pk[1]; u0.z = pk[2]; u0.w = pk[3];
    uint4 u1; u1.x = pk[4]; u1.y = pk[5]; u1.z = pk[6]; u1.w = pk[7];
    *(uint4*)&As[r2*32 + h*16]     = u0;
    *(uint4*)&As[r2*32 + h*16 + 8] = u1;
    const float* gb = Cn + ((size_t)(kk + kr))*N_DIM + bcol + seg*16;
    for (int q = 0; q < 4; ++q){
      float4 f = *(const float4*)(gb + q*4);
      Bs[(seg*16 + q*4 + 0)*32 + kr] = f2bf(f.x);
      Bs[(seg*16 + q*4 + 1)*32 + kr] = f2bf(f.y);
      Bs[(seg*16 + q*4 + 2)*32 + kr] = f2bf(f.z);
      Bs[(seg*16 + q*4 + 3)*32 + kr] = f2bf(f.w);
    }
    __syncthreads();
    short8 a[4], b[4];
    for (int m = 0; m < 4; ++m) a[m] = *(const short8*)&As[(wr*64 + m*16 + fr)*32 + fq*8];
    for (int n = 0; n < 4; ++n) b[n] = *(const short8*)&Bs[(wc*64 + n*16 + fr)*32 + fq*8];
    for (int m = 0; m < 4; ++m)
      for (int n = 0; n < 4; ++n)
        acc[m][n] = __builtin_amdgcn_mfma_f32_16x16x32_bf16(a[m], b[n], acc[m][n], 0, 0, 0);
  }
  for (int m = 0; m < 4; ++m)
    for (int n = 0; n < 4; ++n){
      int row = brow + wr*64 + m*16 + fq*4;
      int col = bcol + wc*64 + n*16 + fr;
      for (int j = 0; j < 4; ++j)
        out[((size_t)(row + j))*N_DIM + col] = acc[m][n][j];
    }
}

// ---------------- per-row exact top-82 -> one-hot ---------------------------
__device__ __forceinline__ void find_bin(unsigned* hist, unsigned* wtot,
                                         int* pB, int* pK, int tid, int Kt){
  int lane = tid & 63, w = tid >> 6;
  unsigned s = 0;
  #pragma unroll
  for (int b = 0; b < 16; ++b) s += hist[tid*16 + b];
  unsigned S = s;
  #pragma unroll
  for (int off = 1; off < 64; off <<= 1){
    unsigned T = __shfl_down(S, off, 64);
    if (lane + off < 64) S += T;
  }
  if (lane == 0) wtot[w] = S;
  __syncthreads();
  unsigned above = 0;
  for (int w2 = w + 1; w2 < 4; ++w2) above += wtot[w2];
  unsigned St = S + above;
  unsigned Sn = St - s;
  if (St >= (unsigned)Kt && Sn < (unsigned)Kt){
    unsigned cum = Sn;
    for (int b = 15; b >= 0; --b){
      unsigned hb = hist[tid*16 + b];
      cum += hb;
      if (cum >= (unsigned)Kt){ *pB = tid*16 + b; *pK = Kt - (int)(cum - hb); break; }
    }
  }
  __syncthreads();
}

template<typename CT>
__global__ __launch_bounds__(256) void topk_kernel(const CT* __restrict__ cnt,
                                                   float* __restrict__ outp,
                                                   const double* __restrict__ boost){
  __shared__ unsigned hist[4096];
  __shared__ unsigned wtot[4];
  __shared__ int sB, sK, sB2, sK2, scnt, sTi;
  __shared__ u64 sTv;
  __shared__ u64 cbits[256];
  __shared__ int cidx[256];
  int tid = threadIdx.x;
  const CT* rp = cnt + (size_t)blockIdx.x * N_DIM;
  float* wp = outp + (size_t)blockIdx.x * N_DIM;

  double v[16];
  unsigned bin[16];
  #pragma unroll
  for (int g = 0; g < 4; ++g){
    int c0 = g*1024 + tid*4;
    double4 bf = *(const double4*)&boost[c0];
    if constexpr (sizeof(CT) == 2){
      ushort4 f = *(const ushort4*)&rp[c0];
      v[g*4+0] = (double)f.x * bf.x;
      v[g*4+1] = (double)f.y * bf.y;
      v[g*4+2] = (double)f.z * bf.z;
      v[g*4+3] = (double)f.w * bf.w;
    } else {
      float4 f = *(const float4*)&rp[c0];
      v[g*4+0] = (double)f.x * bf.x;
      v[g*4+1] = (double)f.y * bf.y;
      v[g*4+2] = (double)f.z * bf.z;
      v[g*4+3] = (double)f.w * bf.w;
    }
  }
  #pragma unroll
  for (int e = 0; e < 16; ++e)
    bin[e] = (unsigned)(((u64)__double_as_longlong(v[e])) >> 51) & 4095u;

  #pragma unroll
  for (int i = 0; i < 16; ++i) hist[tid + 256*i] = 0u;
  __syncthreads();
  #pragma unroll
  for (int e = 0; e < 16; ++e) atomicAdd(&hist[bin[e]], 1u);
  __syncthreads();

  find_bin(hist, wtot, &sB, &sK, tid, TOPK);
  int B = sB, k1 = sK;

  #pragma unroll
  for (int i = 0; i < 16; ++i) hist[tid + 256*i] = 0u;
  if (tid == 0) scnt = 0;
  __syncthreads();
  #pragma unroll
  for (int e = 0; e < 16; ++e){
    if (bin[e] == (unsigned)B){
      unsigned b2 = (unsigned)(((u64)__double_as_longlong(v[e])) >> 39) & 4095u;
      atomicAdd(&hist[b2], 1u);
    }
  }
  __syncthreads();

  find_bin(hist, wtot, &sB2, &sK2, tid, k1);
  int B2 = sB2, k2 = sK2;

  #pragma unroll
  for (int e = 0; e < 16; ++e){
    if (bin[e] == (unsigned)B){
      u64 ub = (u64)__double_as_longlong(v[e]);
      if ((unsigned)((ub >> 39) & 4095u) == (unsigned)B2){
        int pos = atomicAdd(&scnt, 1);
        if (pos < 256){
          int g = e >> 2, j = e & 3;
          cbits[pos] = ub;
          cidx[pos] = g*1024 + tid*4 + j;
        }
      }
    }
  }
  __syncthreads();
  int Csz = scnt; if (Csz > 256) Csz = 256;
  for (int i = tid; i < Csz; i += 256){
    u64 bi = cbits[i]; int xi = cidx[i];
    int rk = 0;
    for (int j2 = 0; j2 < Csz; ++j2){
      u64 bj = cbits[j2];
      rk += (int)((bj > bi) || (bj == bi && cidx[j2] < xi));
    }
    if (rk == k2 - 1){ sTv = bi; sTi = xi; }
  }
  __syncthreads();
  double Tv = __longlong_as_double((long long)sTv);
  int Ti = sTi;
  #pragma unroll
  for (int g = 0; g < 4; ++g){
    int c0 = g*1024 + tid*4;
    float4 o;
    o.x = (v[g*4+0] > Tv || (v[g*4+0] == Tv && (c0+0) <= Ti)) ? 1.0f : 0.0f;
    o.y = (v[g*4+1] > Tv || (v[g*4+1] == Tv && (c0+1) <= Ti)) ? 1.0f : 0.0f;
    o.z = (v[g*4+2] > Tv || (v[g*4+2] == Tv && (c0+2) <= Ti)) ? 1.0f : 0.0f;
    o.w = (v[g*4+3] > Tv || (v[g*4+3] == Tv && (c0+3) <= Ti)) ? 1.0f : 0.0f;
    *(float4*)&wp[c0] = o;
  }
}

extern "C" void kernel_launch(void* const* d_in, const int* in_sizes, int n_in,
                              void* d_out, int out_size, void* d_ws, size_t ws_size,
                              hipStream_t stream){
  (void)in_sizes; (void)n_in; (void)out_size;
  const float* X   = (const float*)d_in[0];   // x [8192][2048]
  const float* Cn  = (const float*)d_in[1];   // connection [2048][4096]
  const float* avg = (const float*)d_in[2];   // avg_activation [4096]
  float* out = (float*)d_out;                 // [8192][4096]
  char* ws = (char*)d_ws;

  double* boost = (double*)ws;                                          // 32 KB
  const size_t offA = 65536;
  unsigned char* A8 = (unsigned char*)(ws + offA);                      // 16 MB
  unsigned char* B8 = (unsigned char*)(ws + offA + (size_t)16777216);   //  8 MB
  unsigned short* CNT = (unsigned short*)(ws + offA + (size_t)25165824);// 64 MB
  const size_t need_mid  = offA + (size_t)25165824;
  const size_t need_full = need_mid + (size_t)67108864;

  if (ws_size >= need_full){
    prep_kernel<<<dim3(4609), dim3(256), 0, stream>>>(X, Cn, avg, A8, B8, boost);
    gemm4_kernel<<<dim3(512), dim3(512), 0, stream>>>(A8, B8, CNT);
    topk_kernel<unsigned short><<<dim3(8192), dim3(256), 0, stream>>>(CNT, out, boost);
  } else if (ws_size >= need_mid){
    prep_kernel<<<dim3(4609), dim3(256), 0, stream>>>(X, Cn, avg, A8, B8, boost);
    gemm2_kernel<float><<<dim3(512), dim3(512), 0, stream>>>(A8, B8, out);
    topk_kernel<float><<<dim3(8192), dim3(256), 0, stream>>>(out, out, boost);
  } else {
    prep_kernel<<<dim3(4609), dim3(256), 0, stream>>>(X, Cn, avg, A8, B8, boost);
    gemm_fb_kernel<<<dim3(2048), dim3(256), 0, stream>>>(X, Cn, out);
    topk_kernel<float><<<dim3(8192), dim3(256), 0, stream>>>(out, out, boost);
  }
}